// Round 26
// baseline (134.781 us; speedup 1.0000x reference)
//
#include <hip/hip_runtime.h>

#define Bdim 2
#define Sdim 2048
#define Ddim 1024
#define Hdim 16

typedef unsigned short u16;
typedef u16 u16x8 __attribute__((ext_vector_type(8)));
typedef u16 u16x4 __attribute__((ext_vector_type(4)));
typedef unsigned u32x4 __attribute__((ext_vector_type(4)));
typedef __bf16 bf16x8 __attribute__((ext_vector_type(8)));
typedef float f32x4 __attribute__((ext_vector_type(4)));
typedef float f32x16 __attribute__((ext_vector_type(16)));

static __device__ __forceinline__ u16 f2bf(float f) {
  unsigned u = __float_as_uint(f);
  u += 0x7fffu + ((u >> 16) & 1u);
  return (u16)(u >> 16);
}
static __device__ __forceinline__ float bf2f(u16 v) {
  return __uint_as_float((unsigned)v << 16);
}
static __device__ __forceinline__ bf16x8 asbf(u16x8 v) {
  return __builtin_bit_cast(bf16x8, v);
}
static __device__ __forceinline__ f32x4 mfma16(bf16x8 a, bf16x8 b, f32x4 c) {
  return __builtin_amdgcn_mfma_f32_16x16x32_bf16(a, b, c, 0, 0, 0);
}
static __device__ __forceinline__ f32x16 mfma32(bf16x8 a, bf16x8 b, f32x16 c) {
  return __builtin_amdgcn_mfma_f32_32x32x16_bf16(a, b, c, 0, 0, 0);
}

// Staging-order tile cell for [rows][1024] bf16 (gemm operand layout, r16-verified):
// tcell(R,k) = ((R>>7)*16 + (k>>6))*1024 + (R&127)*8 + ((k>>3)&7), cell = 8 u16.
static __device__ __forceinline__ size_t tcell(int R, int k) {
  return ((size_t)(R >> 7) * 16 + (k >> 6)) * 1024 + (R & 127) * 8 + ((k >> 3) & 7);
}

// ---------------- cast x (f32 -> bf16) into staging-tiled layout ----------------
__global__ __launch_bounds__(256) void cvtx(const float* __restrict__ x,
                                            u16* __restrict__ xt) {
  int i = blockIdx.x * 256 + threadIdx.x;  // row-major cell id over [4096][1024]
  const float4* xp = (const float4*)x;
  float4 a = xp[2 * i], b = xp[2 * i + 1];
  u16x8 o;
  o[0] = f2bf(a.x); o[1] = f2bf(a.y); o[2] = f2bf(a.z); o[3] = f2bf(a.w);
  o[4] = f2bf(b.x); o[5] = f2bf(b.y); o[6] = f2bf(b.z); o[7] = f2bf(b.w);
  int R = i >> 7, k = (i & 127) * 8;
  ((u16x8*)xt)[tcell(R, k)] = o;
}

// ------ transpose + cast W [K][N] f32 -> staging-tiled WT (rows = N) ------
__global__ __launch_bounds__(256) void transw(
    const float* __restrict__ W0, const float* __restrict__ W1,
    const float* __restrict__ W2, const float* __restrict__ W3,
    u16* __restrict__ T0, u16* __restrict__ T1,
    u16* __restrict__ T2, u16* __restrict__ T3) {
  const float* W = blockIdx.z == 0 ? W0 : blockIdx.z == 1 ? W1 : blockIdx.z == 2 ? W2 : W3;
  u16* T = blockIdx.z == 0 ? T0 : blockIdx.z == 1 ? T1 : blockIdx.z == 2 ? T2 : T3;
  __shared__ float tile[32][33];
  const int t = threadIdx.x;
  const int k0 = blockIdx.x * 32, n0 = blockIdx.y * 32;
  const int r = t >> 3, cq = (t & 7) * 4;
  float4 v = *(const float4*)(W + (size_t)(k0 + r) * Ddim + n0 + cq);
  tile[r][cq] = v.x; tile[r][cq + 1] = v.y; tile[r][cq + 2] = v.z; tile[r][cq + 3] = v.w;
  __syncthreads();
  u16x4 ov;
  ov[0] = f2bf(tile[cq][r]);
  ov[1] = f2bf(tile[cq + 1][r]);
  ov[2] = f2bf(tile[cq + 2][r]);
  ov[3] = f2bf(tile[cq + 3][r]);
  int n = n0 + r, k = k0 + cq;
  *(u16x4*)(T + tcell(n, k) * 8 + (k & 7)) = ov;
}

// ---------------- QKV GEMM: 128x128 tiles (r25-verified ~35us), attn-tiled outputs ----------------
__global__ __launch_bounds__(256) void gemm_qkv(
    const u16* __restrict__ A,
    const u16* __restrict__ Bt0, const u16* __restrict__ Bt1, const u16* __restrict__ Bt2,
    u16* __restrict__ Qt, u16* __restrict__ Kt, u16* __restrict__ Vt) {
  __shared__ u16 As[128 * 64];
  __shared__ u16 Bs[128 * 64];
  const int zz = blockIdx.y >> 3;
  const u16* Bt = (zz == 0) ? Bt0 : (zz == 1) ? Bt1 : Bt2;

  const int t = threadIdx.x;
  const int lane = t & 63, w = t >> 6;
  const int wm = w >> 1, wn = w & 1;
  const int c = lane & 15, g = lane >> 4;
  const int mb = blockIdx.x, nb = blockIdx.y & 7;
  const float oscale = (zz == 0) ? 0.125f : 1.0f;

  const f32x4 zv = {0.f, 0.f, 0.f, 0.f};
  f32x4 acc[4][4];
#pragma unroll
  for (int m = 0; m < 4; m++)
#pragma unroll
    for (int n = 0; n < 4; n++) acc[m][n] = zv;

  const u16x8* Ac = (const u16x8*)A;
  const u16x8* Bc = (const u16x8*)Bt;
  u16x8 ra[4], rb[4];
#pragma unroll
  for (int i = 0; i < 4; i++) {
    ra[i] = Ac[(size_t)(mb * 16 + 0) * 1024 + t + 256 * i];
    rb[i] = Bc[(size_t)(nb * 16 + 0) * 1024 + t + 256 * i];
  }
#pragma unroll
  for (int i = 0; i < 4; i++) {
    int idx = t + 256 * i;
    int row = idx >> 3, ch = idx & 7;
    int sw = (ch ^ (row & 7)) * 8;
    *(u16x8*)(As + row * 64 + sw) = ra[i];
    *(u16x8*)(Bs + row * 64 + sw) = rb[i];
  }
  __syncthreads();

  for (int kt = 0; kt < 16; ++kt) {
    const bool more = (kt + 1) < 16;
    if (more) {
#pragma unroll
      for (int i = 0; i < 4; i++) {
        ra[i] = Ac[(size_t)(mb * 16 + kt + 1) * 1024 + t + 256 * i];
        rb[i] = Bc[(size_t)(nb * 16 + kt + 1) * 1024 + t + 256 * i];
      }
    }
#pragma unroll
    for (int kh = 0; kh < 2; kh++) {
      bf16x8 af[4], bfr[4];
#pragma unroll
      for (int m = 0; m < 4; m++) {
        int row = wm * 64 + m * 16 + c;
        int chr = kh * 4 + g;
        af[m] = asbf(*(const u16x8*)(As + row * 64 + ((chr ^ (row & 7)) * 8)));
      }
#pragma unroll
      for (int n = 0; n < 4; n++) {
        int row = wn * 64 + n * 16 + c;
        int chr = kh * 4 + g;
        bfr[n] = asbf(*(const u16x8*)(Bs + row * 64 + ((chr ^ (row & 7)) * 8)));
      }
#pragma unroll
      for (int m = 0; m < 4; m++)
#pragma unroll
        for (int n = 0; n < 4; n++) acc[m][n] = mfma16(af[m], bfr[n], acc[m][n]);
    }
    if (more) {
      __syncthreads();
#pragma unroll
      for (int i = 0; i < 4; i++) {
        int idx = t + 256 * i;
        int row = idx >> 3, ch = idx & 7;
        int sw = (ch ^ (row & 7)) * 8;
        *(u16x8*)(As + row * 64 + sw) = ra[i];
        *(u16x8*)(Bs + row * 64 + sw) = rb[i];
      }
      __syncthreads();
    }
  }
  // epilogue: C/D layout col=lane&15, row=4*(lane>>4)+r [m89/m91]
  if (zz < 2) {
    u16* Ct = (zz == 0) ? Qt : Kt;
#pragma unroll
    for (int m = 0; m < 4; m++)
#pragma unroll
      for (int n = 0; n < 4; n++) {
        int col = nb * 128 + wn * 64 + n * 16 + c;
        int Rb = mb * 128 + wm * 64 + m * 16 + 4 * g;
        size_t base = ((size_t)((Rb >> 11) * 16 + (col >> 6)) * 32 + ((Rb >> 6) & 31)) * 4096 +
                      ((col & 63) >> 3) * 512 + (size_t)(Rb & 63) * 8 + (col & 7);
#pragma unroll
        for (int r = 0; r < 4; r++)
          Ct[base + (size_t)r * 8] = f2bf(acc[m][n][r] * oscale);
      }
  } else {
#pragma unroll
    for (int m = 0; m < 4; m++)
#pragma unroll
      for (int n = 0; n < 4; n++) {
        int col = nb * 128 + wn * 64 + n * 16 + c;
        int Rb = mb * 128 + wm * 64 + m * 16 + 4 * g;
        u16x4 ov;
#pragma unroll
        for (int r = 0; r < 4; r++) ov[r] = f2bf(acc[m][n][r]);
        size_t addr = ((size_t)((Rb >> 11) * 16 + (col >> 6)) * 32 + ((Rb >> 6) & 31)) * 4096 +
                      ((Rb & 63) >> 3) * 512 + (size_t)(col & 63) * 8 + (Rb & 7);
        *(u16x4*)(Vt + addr) = ov;
      }
  }
}

// ------- 64x64 Wo GEMM with FUSED split-combine in the A-staging path -------
// A-tile for K-step kt = attention output of head kt. Instead of reading the
// combined Obt (written by attn_combine), stage A by loading the NS Opart
// chunks + (m,l) and merging in-register (identical f32 math -> same absmax).
// Kills the combine dispatch + the 16MB Obt write + read. MFMA/B/epilogue
// identical to the r24/r25-verified 64x64 gemm_wo.
template <int NS>
__global__ __launch_bounds__(256) void gemm_wo_merge(
    const u16* __restrict__ Opart, const float2* __restrict__ mlp,
    const u16* __restrict__ Bt, float* __restrict__ C) {
  __shared__ u16 As[64 * 64];
  __shared__ u16 Bs[64 * 64];
  const int t = threadIdx.x;
  const int lane = t & 63, w = t >> 6;
  const int wm = w >> 1, wn = w & 1;
  const int c = lane & 15, g = lane >> 4;
  const int mb = blockIdx.x, nb = blockIdx.y;  // 64 m-tiles, 16 n-tiles
  const int r0 = t >> 3, ch = t & 7;           // staging: 2 rows r0,r0+32; chunk ch
  const int bb = mb >> 5;                      // batch of this row-tile
  const int qb = (mb & 31) * 64;               // q base within batch

  const f32x4 zv = {0.f, 0.f, 0.f, 0.f};
  f32x4 acc[2][2];
#pragma unroll
  for (int m = 0; m < 2; m++)
#pragma unroll
    for (int n = 0; n < 2; n++) acc[m][n] = zv;

  const u16x8* Bc = (const u16x8*)Bt;
  const size_t bbase = (size_t)(nb >> 1) * 16384 + (size_t)(nb & 1) * 512;

  u16x8 rap[2][NS];
  float2 ml[2][NS];
  u16x8 rb[2];

#define LOADA_WO(ktv)                                                          \
  _Pragma("unroll") for (int i = 0; i < 2; i++) {                              \
    int q = qb + r0 + 32 * i;                                                  \
    _Pragma("unroll") for (int z = 0; z < NS; z++) {                           \
      size_t base = (size_t)(z * 32 + bb * 16 + (ktv)) * 2048 + q;             \
      rap[i][z] = *(const u16x8*)(Opart + base * 64 + ch * 8);                 \
      ml[i][z] = mlp[base];                                                    \
    }                                                                          \
  }
#define MERGEA_WO()                                                            \
  _Pragma("unroll") for (int i = 0; i < 2; i++) {                              \
    float M = -3.0e38f;                                                        \
    _Pragma("unroll") for (int z = 0; z < NS; z++) M = fmaxf(M, ml[i][z].x);   \
    float wt[NS], wsum = 0.f;                                                  \
    _Pragma("unroll") for (int z = 0; z < NS; z++) {                           \
      wt[z] = __expf(ml[i][z].x - M);                                          \
      wsum += wt[z] * ml[i][z].y;                                              \
    }                                                                          \
    float inv = 1.f / wsum;                                                    \
    u16x8 res;                                                                 \
    _Pragma("unroll") for (int e = 0; e < 8; e++) {                            \
      float a = 0.f;                                                           \
      _Pragma("unroll") for (int z = 0; z < NS; z++)                           \
        a += wt[z] * bf2f(rap[i][z][e]);                                       \
      res[e] = f2bf(a * inv);                                                  \
    }                                                                          \
    int row = r0 + 32 * i;                                                     \
    *(u16x8*)(As + row * 64 + ((ch ^ (row & 7)) * 8)) = res;                   \
  }

  LOADA_WO(0);
#pragma unroll
  for (int i = 0; i < 2; i++) rb[i] = Bc[bbase + 0 * 1024 + t + 256 * i];
  MERGEA_WO();
#pragma unroll
  for (int i = 0; i < 2; i++) {
    int idx = t + 256 * i;
    int row = idx >> 3, chb = idx & 7;
    *(u16x8*)(Bs + row * 64 + ((chb ^ (row & 7)) * 8)) = rb[i];
  }
  __syncthreads();

  for (int kt = 0; kt < 16; ++kt) {
    const bool more = (kt + 1) < 16;
    if (more) {
      LOADA_WO(kt + 1);
#pragma unroll
      for (int i = 0; i < 2; i++)
        rb[i] = Bc[bbase + (size_t)(kt + 1) * 1024 + t + 256 * i];
    }
#pragma unroll
    for (int kh = 0; kh < 2; kh++) {
      bf16x8 af[2], bfr[2];
#pragma unroll
      for (int m = 0; m < 2; m++) {
        int row = wm * 32 + m * 16 + c;
        int chr = kh * 4 + g;
        af[m] = asbf(*(const u16x8*)(As + row * 64 + ((chr ^ (row & 7)) * 8)));
      }
#pragma unroll
      for (int n = 0; n < 2; n++) {
        int row = wn * 32 + n * 16 + c;
        int chr = kh * 4 + g;
        bfr[n] = asbf(*(const u16x8*)(Bs + row * 64 + ((chr ^ (row & 7)) * 8)));
      }
#pragma unroll
      for (int m = 0; m < 2; m++)
#pragma unroll
        for (int n = 0; n < 2; n++) acc[m][n] = mfma16(af[m], bfr[n], acc[m][n]);
    }
    if (more) {
      __syncthreads();
      MERGEA_WO();
#pragma unroll
      for (int i = 0; i < 2; i++) {
        int idx = t + 256 * i;
        int row = idx >> 3, chb = idx & 7;
        *(u16x8*)(Bs + row * 64 + ((chb ^ (row & 7)) * 8)) = rb[i];
      }
      __syncthreads();
    }
  }
#pragma unroll
  for (int m = 0; m < 2; m++)
#pragma unroll
    for (int n = 0; n < 2; n++)
#pragma unroll
      for (int r = 0; r < 4; r++) {
        int row = mb * 64 + wm * 32 + m * 16 + 4 * g + r;
        int col = nb * 64 + wn * 32 + n * 16 + c;
        C[(size_t)row * 1024 + col] = acc[m][n][r];
      }
#undef LOADA_WO
#undef MERGEA_WO
}

// ---- plain 64x64 Wo GEMM (NS==1 fallback; reads combined Obt) ----
__global__ __launch_bounds__(256) void gemm_wo_plain(
    const u16* __restrict__ A, const u16* __restrict__ Bt, float* __restrict__ C) {
  __shared__ u16 As[64 * 64];
  __shared__ u16 Bs[64 * 64];
  const int t = threadIdx.x;
  const int lane = t & 63, w = t >> 6;
  const int wm = w >> 1, wn = w & 1;
  const int c = lane & 15, g = lane >> 4;
  const int mb = blockIdx.x, nb = blockIdx.y;

  const f32x4 zv = {0.f, 0.f, 0.f, 0.f};
  f32x4 acc[2][2];
#pragma unroll
  for (int m = 0; m < 2; m++)
#pragma unroll
    for (int n = 0; n < 2; n++) acc[m][n] = zv;

  const u16x8* Ac = (const u16x8*)A;
  const u16x8* Bc = (const u16x8*)Bt;
  const size_t abase = (size_t)(mb >> 1) * 16384 + (size_t)(mb & 1) * 512;
  const size_t bbase = (size_t)(nb >> 1) * 16384 + (size_t)(nb & 1) * 512;
  u16x8 ra[2], rb[2];
#pragma unroll
  for (int i = 0; i < 2; i++) {
    ra[i] = Ac[abase + 0 * 1024 + t + 256 * i];
    rb[i] = Bc[bbase + 0 * 1024 + t + 256 * i];
  }
#pragma unroll
  for (int i = 0; i < 2; i++) {
    int idx = t + 256 * i;
    int row = idx >> 3, ch = idx & 7;
    int sw = (ch ^ (row & 7)) * 8;
    *(u16x8*)(As + row * 64 + sw) = ra[i];
    *(u16x8*)(Bs + row * 64 + sw) = rb[i];
  }
  __syncthreads();

  for (int kt = 0; kt < 16; ++kt) {
    const bool more = (kt + 1) < 16;
    if (more) {
#pragma unroll
      for (int i = 0; i < 2; i++) {
        ra[i] = Ac[abase + (size_t)(kt + 1) * 1024 + t + 256 * i];
        rb[i] = Bc[bbase + (size_t)(kt + 1) * 1024 + t + 256 * i];
      }
    }
#pragma unroll
    for (int kh = 0; kh < 2; kh++) {
      bf16x8 af[2], bfr[2];
#pragma unroll
      for (int m = 0; m < 2; m++) {
        int row = wm * 32 + m * 16 + c;
        int chr = kh * 4 + g;
        af[m] = asbf(*(const u16x8*)(As + row * 64 + ((chr ^ (row & 7)) * 8)));
      }
#pragma unroll
      for (int n = 0; n < 2; n++) {
        int row = wn * 32 + n * 16 + c;
        int chr = kh * 4 + g;
        bfr[n] = asbf(*(const u16x8*)(Bs + row * 64 + ((chr ^ (row & 7)) * 8)));
      }
#pragma unroll
      for (int m = 0; m < 2; m++)
#pragma unroll
        for (int n = 0; n < 2; n++) acc[m][n] = mfma16(af[m], bfr[n], acc[m][n]);
    }
    if (more) {
      __syncthreads();
#pragma unroll
      for (int i = 0; i < 2; i++) {
        int idx = t + 256 * i;
        int row = idx >> 3, ch = idx & 7;
        int sw = (ch ^ (row & 7)) * 8;
        *(u16x8*)(As + row * 64 + sw) = ra[i];
        *(u16x8*)(Bs + row * 64 + sw) = rb[i];
      }
      __syncthreads();
    }
  }
#pragma unroll
  for (int m = 0; m < 2; m++)
#pragma unroll
    for (int n = 0; n < 2; n++)
#pragma unroll
      for (int r = 0; r < 4; r++) {
        int row = mb * 64 + wm * 32 + m * 16 + 4 * g + r;
        int col = nb * 64 + wn * 32 + n * 16 + c;
        C[(size_t)row * 1024 + col] = acc[m][n][r];
      }
}

// ---------------- flash attention: all operands tiled (Qt/Kt/Vt) + KV-split ----------------
__global__ __launch_bounds__(64, 4) void attn_kernel(
    const u16* __restrict__ Qt, const u16* __restrict__ Kt,
    const u16* __restrict__ Vt, const int* __restrict__ vlen,
    u16* __restrict__ O, u16* __restrict__ Opart, float2* __restrict__ mlp) {
  __shared__ u16 ot[32][72];
  const int lane = threadIdx.x;
  const int q = lane & 31, hi = lane >> 5;
  const int bh = blockIdx.y, b = bh >> 4, h = bh & 15;
  const int q0 = blockIdx.x * 32;
  const int nv = vlen[b];
  const int NS = gridDim.z, z = blockIdx.z;

  bf16x8 qf[4];
  {
    const u16* Qtile = Qt + ((size_t)bh * 32 + (q0 >> 6)) * 4096;
    int qrow = (q0 & 63) + q;
#pragma unroll
    for (int s = 0; s < 4; s++)
      qf[s] = asbf(*(const u16x8*)(Qtile + (2 * s + hi) * 512 + qrow * 8));
  }

  f32x16 o0, o1;
#pragma unroll
  for (int r = 0; r < 16; r++) { o0[r] = 0.f; o1[r] = 0.f; }
  float m = -3.0e38f, l = 0.f;

  const int nt = (nv + 63) >> 6;
  const int chunk = (nt + NS - 1) / NS;
  const int t0 = z * chunk;
  const int t1 = min(nt, t0 + chunk);
  for (int kt = t0; kt < t1; ++kt) {
    const int k0 = kt * 64;
    const u16* Ktile = Kt + ((size_t)bh * 32 + kt) * 4096;
    const u16* Vtile = Vt + ((size_t)bh * 32 + kt) * 4096;
    f32x16 sc[2];
#pragma unroll
    for (int kb = 0; kb < 2; kb++) {
      f32x16 acc;
#pragma unroll
      for (int r = 0; r < 16; r++) acc[r] = 0.f;
#pragma unroll
      for (int s = 0; s < 4; s++) {
        bf16x8 kf = asbf(*(const u16x8*)(Ktile + (2 * s + hi) * 512 + (kb * 32 + q) * 8));
        acc = mfma32(kf, qf[s], acc);
      }
      sc[kb] = acc;
    }
    if (k0 + 64 > nv) {
#pragma unroll
      for (int kb = 0; kb < 2; kb++)
#pragma unroll
        for (int r = 0; r < 16; r++) {
          int key = k0 + kb * 32 + (r & 3) + 8 * (r >> 2) + 4 * hi;
          if (key >= nv) sc[kb][r] = -1e30f;
        }
    }
    float mx[16];
#pragma unroll
    for (int r = 0; r < 16; r++) mx[r] = fmaxf(sc[0][r], sc[1][r]);
#pragma unroll
    for (int st = 8; st > 0; st >>= 1)
#pragma unroll
      for (int r = 0; r < st; r++) mx[r] = fmaxf(mx[r], mx[r + st]);
    float tm = fmaxf(mx[0], __shfl_xor(mx[0], 32));
    if (!__all(tm <= m + 8.f)) {
      float mn = fmaxf(m, tm);
      float al = __expf(m - mn);
#pragma unroll
      for (int r = 0; r < 16; r++) { o0[r] *= al; o1[r] *= al; }
      l *= al;
      m = mn;
    }
    unsigned pw[4][4];
    float s0 = 0.f, s1 = 0.f, s2 = 0.f, s3 = 0.f;
#pragma unroll
    for (int kb = 0; kb < 2; kb++)
#pragma unroll
      for (int hh = 0; hh < 2; hh++)
#pragma unroll
        for (int wi = 0; wi < 4; wi++) {
          float e0 = __expf(sc[kb][hh * 8 + wi * 2] - m);
          float e1 = __expf(sc[kb][hh * 8 + wi * 2 + 1] - m);
          if (wi == 0) s0 += e0 + e1;
          else if (wi == 1) s1 += e0 + e1;
          else if (wi == 2) s2 += e0 + e1;
          else s3 += e0 + e1;
          asm("v_cvt_pk_bf16_f32 %0, %1, %2"
              : "=v"(pw[kb * 2 + hh][wi]) : "v"(e0), "v"(e1));
        }
    float ssum = (s0 + s1) + (s2 + s3);
    ssum += __shfl_xor(ssum, 32);
    l += ssum;
#pragma unroll
    for (int f = 0; f < 4; f++) {
      asm("v_permlane32_swap_b32 %0, %1" : "+v"(pw[f][0]), "+v"(pw[f][2]));
      asm("v_permlane32_swap_b32 %0, %1" : "+v"(pw[f][1]), "+v"(pw[f][3]));
    }
#pragma unroll
    for (int f = 0; f < 4; f++) {
      u32x4 wv = {pw[f][0], pw[f][1], pw[f][2], pw[f][3]};
      bf16x8 pa = __builtin_bit_cast(bf16x8, wv);
      bf16x8 va = asbf(*(const u16x8*)(Vtile + (2 * f + hi) * 512 + q * 8));
      bf16x8 vb = asbf(*(const u16x8*)(Vtile + (2 * f + hi) * 512 + (32 + q) * 8));
      o0 = mfma32(va, pa, o0);
      o1 = mfma32(vb, pa, o1);
    }
  }
  const float scale = (NS == 1) ? (1.f / l) : 1.f;
#pragma unroll
  for (int r = 0; r < 16; r++) {
    const int dh = (r & 3) + 8 * (r >> 2) + 4 * hi;
    ot[q][dh] = f2bf(o0[r] * scale);
    ot[q][32 + dh] = f2bf(o1[r] * scale);
  }
  asm volatile("s_waitcnt lgkmcnt(0)" ::: "memory");
  __builtin_amdgcn_sched_barrier(0);
  if (NS == 1) {
    int R = b * Sdim + q0 + q;
    size_t cellbase = ((size_t)(R >> 7) * 16 + h) * 1024 + (R & 127) * 8 + hi * 4;
#pragma unroll
    for (int j = 0; j < 4; j++)
      ((u16x8*)O)[cellbase + j] = *(const u16x8*)(&ot[q][hi * 32 + j * 8]);
  } else {
    u16* op = Opart + ((size_t)(z * 32 + bh) * Sdim + q0 + q) * 64 + hi * 32;
#pragma unroll
    for (int j = 0; j < 4; j++)
      *(u16x8*)(op + j * 8) = *(const u16x8*)(&ot[q][hi * 32 + j * 8]);
    if (hi == 0)
      mlp[(size_t)(z * 32 + bh) * Sdim + q0 + q] = make_float2(m, l);
  }
}

extern "C" void kernel_launch(void* const* d_in, const int* in_sizes, int n_in,
                              void* d_out, int out_size, void* d_ws, size_t ws_size,
                              hipStream_t stream) {
  const float* x = (const float*)d_in[0];
  const float* Wq = (const float*)d_in[1];
  const float* Wk = (const float*)d_in[2];
  const float* Wv = (const float*)d_in[3];
  const float* Wo = (const float*)d_in[4];
  const int* vl = (const int*)d_in[5];
  float* out = (float*)d_out;

  char* ws = (char*)d_ws;
  const size_t SZ_X = (size_t)Bdim * Sdim * Ddim * sizeof(u16);  // 8 MB
  const size_t SZ_W = (size_t)Ddim * Ddim * sizeof(u16);         // 2 MB
  u16* xt = (u16*)ws; ws += SZ_X;   // staging-tiled x
  u16* WqT = (u16*)ws; ws += SZ_W;  // staging-tiled weights
  u16* WkT = (u16*)ws; ws += SZ_W;
  u16* WvT = (u16*)ws; ws += SZ_W;
  u16* WoT = (u16*)ws; ws += SZ_W;
  u16* Qtb = (u16*)ws; ws += SZ_X;  // attn-tiled Q (Kt layout)
  u16* Ktb = (u16*)ws; ws += SZ_X;  // attn-tiled K
  u16* Vtb = (u16*)ws; ws += SZ_X;  // attn-tiled V^T
  u16* Obt = (u16*)ws; ws += SZ_X;  // combined O (NS==1 fallback only)

  const size_t PER_SPLIT = (size_t)Bdim * Hdim * Sdim * 64 * sizeof(u16) +
                           (size_t)Bdim * Hdim * Sdim * sizeof(float2);
  size_t used = (size_t)(ws - (char*)d_ws);
  size_t avail = (ws_size > used) ? ws_size - used : 0;
  int NS = (avail >= 4 * PER_SPLIT) ? 4 : (avail >= 2 * PER_SPLIT) ? 2 : 1;
  u16* Opart = (u16*)ws;
  float2* mlp = (float2*)(ws + (size_t)NS * Bdim * Hdim * Sdim * 64 * sizeof(u16));

  cvtx<<<dim3((Bdim * Sdim * Ddim) / (8 * 256)), 256, 0, stream>>>(x, xt);
  transw<<<dim3(32, 32, 4), 256, 0, stream>>>(Wq, Wk, Wv, Wo, WqT, WkT, WvT, WoT);
  gemm_qkv<<<dim3(32, 24), 256, 0, stream>>>(xt, WqT, WkT, WvT, Qtb, Ktb, Vtb);
  attn_kernel<<<dim3(Sdim / 32, Bdim * Hdim, NS), 64, 0, stream>>>(Qtb, Ktb, Vtb, vl, Obt,
                                                                   Opart, mlp);
  if (NS == 4)
    gemm_wo_merge<4><<<dim3(64, 16), 256, 0, stream>>>(Opart, mlp, WoT, out);
  else if (NS == 2)
    gemm_wo_merge<2><<<dim3(64, 16), 256, 0, stream>>>(Opart, mlp, WoT, out);
  else
    gemm_wo_plain<<<dim3(64, 16), 256, 0, stream>>>(Obt, WoT, out);
}

// Round 27
// 109.020 us; speedup vs baseline: 1.2363x; 1.2363x over previous
//
#include <hip/hip_runtime.h>

#define Bdim 2
#define Sdim 2048
#define Ddim 1024
#define Hdim 16

typedef unsigned short u16;
typedef u16 u16x8 __attribute__((ext_vector_type(8)));
typedef u16 u16x4 __attribute__((ext_vector_type(4)));
typedef unsigned u32x4 __attribute__((ext_vector_type(4)));
typedef __bf16 bf16x8 __attribute__((ext_vector_type(8)));
typedef float f32x4 __attribute__((ext_vector_type(4)));
typedef float f32x16 __attribute__((ext_vector_type(16)));

static __device__ __forceinline__ u16 f2bf(float f) {
  unsigned u = __float_as_uint(f);
  u += 0x7fffu + ((u >> 16) & 1u);
  return (u16)(u >> 16);
}
static __device__ __forceinline__ float bf2f(u16 v) {
  return __uint_as_float((unsigned)v << 16);
}
static __device__ __forceinline__ bf16x8 asbf(u16x8 v) {
  return __builtin_bit_cast(bf16x8, v);
}
static __device__ __forceinline__ f32x4 mfma16(bf16x8 a, bf16x8 b, f32x4 c) {
  return __builtin_amdgcn_mfma_f32_16x16x32_bf16(a, b, c, 0, 0, 0);
}
static __device__ __forceinline__ f32x16 mfma32(bf16x8 a, bf16x8 b, f32x16 c) {
  return __builtin_amdgcn_mfma_f32_32x32x16_bf16(a, b, c, 0, 0, 0);
}

// Staging-order tile cell for [rows][1024] bf16 (gemm operand layout, r16-verified):
// tcell(R,k) = ((R>>7)*16 + (k>>6))*1024 + (R&127)*8 + ((k>>3)&7), cell = 8 u16.
static __device__ __forceinline__ size_t tcell(int R, int k) {
  return ((size_t)(R >> 7) * 16 + (k >> 6)) * 1024 + (R & 127) * 8 + ((k >> 3) & 7);
}

// ---------------- cast x (f32 -> bf16) into staging-tiled layout ----------------
__global__ __launch_bounds__(256) void cvtx(const float* __restrict__ x,
                                            u16* __restrict__ xt) {
  int i = blockIdx.x * 256 + threadIdx.x;  // row-major cell id over [4096][1024]
  const float4* xp = (const float4*)x;
  float4 a = xp[2 * i], b = xp[2 * i + 1];
  u16x8 o;
  o[0] = f2bf(a.x); o[1] = f2bf(a.y); o[2] = f2bf(a.z); o[3] = f2bf(a.w);
  o[4] = f2bf(b.x); o[5] = f2bf(b.y); o[6] = f2bf(b.z); o[7] = f2bf(b.w);
  int R = i >> 7, k = (i & 127) * 8;
  ((u16x8*)xt)[tcell(R, k)] = o;
}

// ------ transpose + cast W [K][N] f32 -> staging-tiled WT (rows = N) ------
__global__ __launch_bounds__(256) void transw(
    const float* __restrict__ W0, const float* __restrict__ W1,
    const float* __restrict__ W2, const float* __restrict__ W3,
    u16* __restrict__ T0, u16* __restrict__ T1,
    u16* __restrict__ T2, u16* __restrict__ T3) {
  const float* W = blockIdx.z == 0 ? W0 : blockIdx.z == 1 ? W1 : blockIdx.z == 2 ? W2 : W3;
  u16* T = blockIdx.z == 0 ? T0 : blockIdx.z == 1 ? T1 : blockIdx.z == 2 ? T2 : T3;
  __shared__ float tile[32][33];
  const int t = threadIdx.x;
  const int k0 = blockIdx.x * 32, n0 = blockIdx.y * 32;
  const int r = t >> 3, cq = (t & 7) * 4;
  float4 v = *(const float4*)(W + (size_t)(k0 + r) * Ddim + n0 + cq);
  tile[r][cq] = v.x; tile[r][cq + 1] = v.y; tile[r][cq + 2] = v.z; tile[r][cq + 3] = v.w;
  __syncthreads();
  u16x4 ov;
  ov[0] = f2bf(tile[cq][r]);
  ov[1] = f2bf(tile[cq + 1][r]);
  ov[2] = f2bf(tile[cq + 2][r]);
  ov[3] = f2bf(tile[cq + 3][r]);
  int n = n0 + r, k = k0 + cq;
  *(u16x4*)(T + tcell(n, k) * 8 + (k & 7)) = ov;
}

// ---------------- QKV GEMM: 128x128 tiles (r25-verified ~35us), attn-tiled outputs ----------------
__global__ __launch_bounds__(256) void gemm_qkv(
    const u16* __restrict__ A,
    const u16* __restrict__ Bt0, const u16* __restrict__ Bt1, const u16* __restrict__ Bt2,
    u16* __restrict__ Qt, u16* __restrict__ Kt, u16* __restrict__ Vt) {
  __shared__ u16 As[128 * 64];
  __shared__ u16 Bs[128 * 64];
  const int zz = blockIdx.y >> 3;
  const u16* Bt = (zz == 0) ? Bt0 : (zz == 1) ? Bt1 : Bt2;

  const int t = threadIdx.x;
  const int lane = t & 63, w = t >> 6;
  const int wm = w >> 1, wn = w & 1;
  const int c = lane & 15, g = lane >> 4;
  const int mb = blockIdx.x, nb = blockIdx.y & 7;
  const float oscale = (zz == 0) ? 0.125f : 1.0f;

  const f32x4 zv = {0.f, 0.f, 0.f, 0.f};
  f32x4 acc[4][4];
#pragma unroll
  for (int m = 0; m < 4; m++)
#pragma unroll
    for (int n = 0; n < 4; n++) acc[m][n] = zv;

  const u16x8* Ac = (const u16x8*)A;
  const u16x8* Bc = (const u16x8*)Bt;
  u16x8 ra[4], rb[4];
#pragma unroll
  for (int i = 0; i < 4; i++) {
    ra[i] = Ac[(size_t)(mb * 16 + 0) * 1024 + t + 256 * i];
    rb[i] = Bc[(size_t)(nb * 16 + 0) * 1024 + t + 256 * i];
  }
#pragma unroll
  for (int i = 0; i < 4; i++) {
    int idx = t + 256 * i;
    int row = idx >> 3, ch = idx & 7;
    int sw = (ch ^ (row & 7)) * 8;
    *(u16x8*)(As + row * 64 + sw) = ra[i];
    *(u16x8*)(Bs + row * 64 + sw) = rb[i];
  }
  __syncthreads();

  for (int kt = 0; kt < 16; ++kt) {
    const bool more = (kt + 1) < 16;
    if (more) {
#pragma unroll
      for (int i = 0; i < 4; i++) {
        ra[i] = Ac[(size_t)(mb * 16 + kt + 1) * 1024 + t + 256 * i];
        rb[i] = Bc[(size_t)(nb * 16 + kt + 1) * 1024 + t + 256 * i];
      }
    }
#pragma unroll
    for (int kh = 0; kh < 2; kh++) {
      bf16x8 af[4], bfr[4];
#pragma unroll
      for (int m = 0; m < 4; m++) {
        int row = wm * 64 + m * 16 + c;
        int chr = kh * 4 + g;
        af[m] = asbf(*(const u16x8*)(As + row * 64 + ((chr ^ (row & 7)) * 8)));
      }
#pragma unroll
      for (int n = 0; n < 4; n++) {
        int row = wn * 64 + n * 16 + c;
        int chr = kh * 4 + g;
        bfr[n] = asbf(*(const u16x8*)(Bs + row * 64 + ((chr ^ (row & 7)) * 8)));
      }
#pragma unroll
      for (int m = 0; m < 4; m++)
#pragma unroll
        for (int n = 0; n < 4; n++) acc[m][n] = mfma16(af[m], bfr[n], acc[m][n]);
    }
    if (more) {
      __syncthreads();
#pragma unroll
      for (int i = 0; i < 4; i++) {
        int idx = t + 256 * i;
        int row = idx >> 3, ch = idx & 7;
        int sw = (ch ^ (row & 7)) * 8;
        *(u16x8*)(As + row * 64 + sw) = ra[i];
        *(u16x8*)(Bs + row * 64 + sw) = rb[i];
      }
      __syncthreads();
    }
  }
  // epilogue: C/D layout col=lane&15, row=4*(lane>>4)+r [m89/m91]
  if (zz < 2) {
    u16* Ct = (zz == 0) ? Qt : Kt;
#pragma unroll
    for (int m = 0; m < 4; m++)
#pragma unroll
      for (int n = 0; n < 4; n++) {
        int col = nb * 128 + wn * 64 + n * 16 + c;
        int Rb = mb * 128 + wm * 64 + m * 16 + 4 * g;
        size_t base = ((size_t)((Rb >> 11) * 16 + (col >> 6)) * 32 + ((Rb >> 6) & 31)) * 4096 +
                      ((col & 63) >> 3) * 512 + (size_t)(Rb & 63) * 8 + (col & 7);
#pragma unroll
        for (int r = 0; r < 4; r++)
          Ct[base + (size_t)r * 8] = f2bf(acc[m][n][r] * oscale);
      }
  } else {
#pragma unroll
    for (int m = 0; m < 4; m++)
#pragma unroll
      for (int n = 0; n < 4; n++) {
        int col = nb * 128 + wn * 64 + n * 16 + c;
        int Rb = mb * 128 + wm * 64 + m * 16 + 4 * g;
        u16x4 ov;
#pragma unroll
        for (int r = 0; r < 4; r++) ov[r] = f2bf(acc[m][n][r]);
        size_t addr = ((size_t)((Rb >> 11) * 16 + (col >> 6)) * 32 + ((Rb >> 6) & 31)) * 4096 +
                      ((Rb & 63) >> 3) * 512 + (size_t)(col & 63) * 8 + (Rb & 7);
        *(u16x4*)(Vt + addr) = ov;
      }
  }
}

// ---------------- 64x64-tile GEMM for Wo (f32 out): 1024 blocks = 4/CU (r25-verified) ----------------
__global__ __launch_bounds__(256) void gemm_wo(
    const u16* __restrict__ A, const u16* __restrict__ Bt, float* __restrict__ C) {
  __shared__ u16 As[64 * 64];
  __shared__ u16 Bs[64 * 64];
  const int t = threadIdx.x;
  const int lane = t & 63, w = t >> 6;
  const int wm = w >> 1, wn = w & 1;
  const int c = lane & 15, g = lane >> 4;
  const int mb = blockIdx.x, nb = blockIdx.y;  // 64 m-tiles, 16 n-tiles of 64

  const f32x4 zv = {0.f, 0.f, 0.f, 0.f};
  f32x4 acc[2][2];
#pragma unroll
  for (int m = 0; m < 2; m++)
#pragma unroll
    for (int n = 0; n < 2; n++) acc[m][n] = zv;

  const u16x8* Ac = (const u16x8*)A;
  const u16x8* Bc = (const u16x8*)Bt;
  const size_t abase = (size_t)(mb >> 1) * 16384 + (size_t)(mb & 1) * 512;
  const size_t bbase = (size_t)(nb >> 1) * 16384 + (size_t)(nb & 1) * 512;
  u16x8 ra[2], rb[2];
#pragma unroll
  for (int i = 0; i < 2; i++) {
    ra[i] = Ac[abase + 0 * 1024 + t + 256 * i];
    rb[i] = Bc[bbase + 0 * 1024 + t + 256 * i];
  }
  {
#pragma unroll
    for (int i = 0; i < 2; i++) {
      int idx = t + 256 * i;
      int row = idx >> 3, ch = idx & 7;
      int sw = (ch ^ (row & 7)) * 8;
      *(u16x8*)(As + row * 64 + sw) = ra[i];
      *(u16x8*)(Bs + row * 64 + sw) = rb[i];
    }
  }
  __syncthreads();

  for (int kt = 0; kt < 16; ++kt) {
    const bool more = (kt + 1) < 16;
    if (more) {
#pragma unroll
      for (int i = 0; i < 2; i++) {
        ra[i] = Ac[abase + (size_t)(kt + 1) * 1024 + t + 256 * i];
        rb[i] = Bc[bbase + (size_t)(kt + 1) * 1024 + t + 256 * i];
      }
    }
#pragma unroll
    for (int kh = 0; kh < 2; kh++) {
      bf16x8 af[2], bfr[2];
#pragma unroll
      for (int m = 0; m < 2; m++) {
        int row = wm * 32 + m * 16 + c;
        int chr = kh * 4 + g;
        af[m] = asbf(*(const u16x8*)(As + row * 64 + ((chr ^ (row & 7)) * 8)));
      }
#pragma unroll
      for (int n = 0; n < 2; n++) {
        int row = wn * 32 + n * 16 + c;
        int chr = kh * 4 + g;
        bfr[n] = asbf(*(const u16x8*)(Bs + row * 64 + ((chr ^ (row & 7)) * 8)));
      }
#pragma unroll
      for (int m = 0; m < 2; m++)
#pragma unroll
        for (int n = 0; n < 2; n++) acc[m][n] = mfma16(af[m], bfr[n], acc[m][n]);
    }
    if (more) {
      __syncthreads();
#pragma unroll
      for (int i = 0; i < 2; i++) {
        int idx = t + 256 * i;
        int row = idx >> 3, ch = idx & 7;
        int sw = (ch ^ (row & 7)) * 8;
        *(u16x8*)(As + row * 64 + sw) = ra[i];
        *(u16x8*)(Bs + row * 64 + sw) = rb[i];
      }
      __syncthreads();
    }
  }
#pragma unroll
  for (int m = 0; m < 2; m++)
#pragma unroll
    for (int n = 0; n < 2; n++)
#pragma unroll
      for (int r = 0; r < 4; r++) {
        int row = mb * 64 + wm * 32 + m * 16 + 4 * g + r;
        int col = nb * 64 + wn * 32 + n * 16 + c;
        C[(size_t)row * 1024 + col] = acc[m][n][r];
      }
}

// ---------------- flash attention: all operands tiled (Qt/Kt/Vt) + KV-split ----------------
__global__ __launch_bounds__(64, 4) void attn_kernel(
    const u16* __restrict__ Qt, const u16* __restrict__ Kt,
    const u16* __restrict__ Vt, const int* __restrict__ vlen,
    u16* __restrict__ O, u16* __restrict__ Opart, float2* __restrict__ mlp) {
  __shared__ u16 ot[32][72];
  const int lane = threadIdx.x;
  const int q = lane & 31, hi = lane >> 5;
  const int bh = blockIdx.y, b = bh >> 4, h = bh & 15;
  const int q0 = blockIdx.x * 32;
  const int nv = vlen[b];
  const int NS = gridDim.z, z = blockIdx.z;

  // Q fragments from the Kt-style Qt tile (2x512B contiguous runs per load)
  bf16x8 qf[4];
  {
    const u16* Qtile = Qt + ((size_t)bh * 32 + (q0 >> 6)) * 4096;
    int qrow = (q0 & 63) + q;
#pragma unroll
    for (int s = 0; s < 4; s++)
      qf[s] = asbf(*(const u16x8*)(Qtile + (2 * s + hi) * 512 + qrow * 8));
  }

  f32x16 o0, o1;
#pragma unroll
  for (int r = 0; r < 16; r++) { o0[r] = 0.f; o1[r] = 0.f; }
  float m = -3.0e38f, l = 0.f;

  const int nt = (nv + 63) >> 6;
  const int chunk = (nt + NS - 1) / NS;
  const int t0 = z * chunk;
  const int t1 = min(nt, t0 + chunk);
  for (int kt = t0; kt < t1; ++kt) {
    const int k0 = kt * 64;
    const u16* Ktile = Kt + ((size_t)bh * 32 + kt) * 4096;
    const u16* Vtile = Vt + ((size_t)bh * 32 + kt) * 4096;
    f32x16 sc[2];
#pragma unroll
    for (int kb = 0; kb < 2; kb++) {
      f32x16 acc;
#pragma unroll
      for (int r = 0; r < 16; r++) acc[r] = 0.f;
#pragma unroll
      for (int s = 0; s < 4; s++) {
        bf16x8 kf = asbf(*(const u16x8*)(Ktile + (2 * s + hi) * 512 + (kb * 32 + q) * 8));
        acc = mfma32(kf, qf[s], acc);
      }
      sc[kb] = acc;
    }
    if (k0 + 64 > nv) {
#pragma unroll
      for (int kb = 0; kb < 2; kb++)
#pragma unroll
        for (int r = 0; r < 16; r++) {
          int key = k0 + kb * 32 + (r & 3) + 8 * (r >> 2) + 4 * hi;
          if (key >= nv) sc[kb][r] = -1e30f;
        }
    }
    float mx[16];
#pragma unroll
    for (int r = 0; r < 16; r++) mx[r] = fmaxf(sc[0][r], sc[1][r]);
#pragma unroll
    for (int st = 8; st > 0; st >>= 1)
#pragma unroll
      for (int r = 0; r < st; r++) mx[r] = fmaxf(mx[r], mx[r + st]);
    float tm = fmaxf(mx[0], __shfl_xor(mx[0], 32));
    if (!__all(tm <= m + 8.f)) {
      float mn = fmaxf(m, tm);
      float al = __expf(m - mn);
#pragma unroll
      for (int r = 0; r < 16; r++) { o0[r] *= al; o1[r] *= al; }
      l *= al;
      m = mn;
    }
    unsigned pw[4][4];
    float s0 = 0.f, s1 = 0.f, s2 = 0.f, s3 = 0.f;
#pragma unroll
    for (int kb = 0; kb < 2; kb++)
#pragma unroll
      for (int hh = 0; hh < 2; hh++)
#pragma unroll
        for (int wi = 0; wi < 4; wi++) {
          float e0 = __expf(sc[kb][hh * 8 + wi * 2] - m);
          float e1 = __expf(sc[kb][hh * 8 + wi * 2 + 1] - m);
          if (wi == 0) s0 += e0 + e1;
          else if (wi == 1) s1 += e0 + e1;
          else if (wi == 2) s2 += e0 + e1;
          else s3 += e0 + e1;
          asm("v_cvt_pk_bf16_f32 %0, %1, %2"
              : "=v"(pw[kb * 2 + hh][wi]) : "v"(e0), "v"(e1));
        }
    float ssum = (s0 + s1) + (s2 + s3);
    ssum += __shfl_xor(ssum, 32);
    l += ssum;
#pragma unroll
    for (int f = 0; f < 4; f++) {
      asm("v_permlane32_swap_b32 %0, %1" : "+v"(pw[f][0]), "+v"(pw[f][2]));
      asm("v_permlane32_swap_b32 %0, %1" : "+v"(pw[f][1]), "+v"(pw[f][3]));
    }
#pragma unroll
    for (int f = 0; f < 4; f++) {
      u32x4 wv = {pw[f][0], pw[f][1], pw[f][2], pw[f][3]};
      bf16x8 pa = __builtin_bit_cast(bf16x8, wv);
      bf16x8 va = asbf(*(const u16x8*)(Vtile + (2 * f + hi) * 512 + q * 8));
      bf16x8 vb = asbf(*(const u16x8*)(Vtile + (2 * f + hi) * 512 + (32 + q) * 8));
      o0 = mfma32(va, pa, o0);
      o1 = mfma32(vb, pa, o1);
    }
  }
  const float scale = (NS == 1) ? (1.f / l) : 1.f;
#pragma unroll
  for (int r = 0; r < 16; r++) {
    const int dh = (r & 3) + 8 * (r >> 2) + 4 * hi;
    ot[q][dh] = f2bf(o0[r] * scale);
    ot[q][32 + dh] = f2bf(o1[r] * scale);
  }
  asm volatile("s_waitcnt lgkmcnt(0)" ::: "memory");
  __builtin_amdgcn_sched_barrier(0);
  if (NS == 1) {
    int R = b * Sdim + q0 + q;
    size_t cellbase = ((size_t)(R >> 7) * 16 + h) * 1024 + (R & 127) * 8 + hi * 4;
#pragma unroll
    for (int j = 0; j < 4; j++)
      ((u16x8*)O)[cellbase + j] = *(const u16x8*)(&ot[q][hi * 32 + j * 8]);
  } else {
    u16* op = Opart + ((size_t)(z * 32 + bh) * Sdim + q0 + q) * 64 + hi * 32;
#pragma unroll
    for (int j = 0; j < 4; j++)
      *(u16x8*)(op + j * 8) = *(const u16x8*)(&ot[q][hi * 32 + j * 8]);
    if (hi == 0)
      mlp[(size_t)(z * 32 + bh) * Sdim + q0 + q] = make_float2(m, l);
  }
}

// ---- combine NS split partials -> O in staging-tiled layout (Wo gemm A) ----
template <int NS>
__global__ __launch_bounds__(256) void attn_combine(
    const u16* __restrict__ Opart, const float2* __restrict__ mlp,
    u16* __restrict__ O) {
  const int t = threadIdx.x;
  const int bh = blockIdx.y, b = bh >> 4, h = bh & 15;
  const int q = blockIdx.x * 32 + (t >> 3);
  const int d0 = (t & 7) * 8;
  float2 ml[NS];
  float M = -3.0e38f;
#pragma unroll
  for (int z = 0; z < NS; z++) {
    ml[z] = mlp[(size_t)(z * 32 + bh) * Sdim + q];
    M = fmaxf(M, ml[z].x);
  }
  float acc[8];
#pragma unroll
  for (int i = 0; i < 8; i++) acc[i] = 0.f;
  float wsum = 0.f;
#pragma unroll
  for (int z = 0; z < NS; z++) {
    float w = __expf(ml[z].x - M);
    wsum += w * ml[z].y;
    u16x8 ov = *(const u16x8*)(Opart + ((size_t)(z * 32 + bh) * Sdim + q) * 64 + d0);
#pragma unroll
    for (int i = 0; i < 8; i++) acc[i] += w * bf2f(ov[i]);
  }
  const float inv = 1.f / wsum;
  u16x8 res;
#pragma unroll
  for (int i = 0; i < 8; i++) res[i] = f2bf(acc[i] * inv);
  int R = b * Sdim + q;
  ((u16x8*)O)[((size_t)(R >> 7) * 16 + h) * 1024 + (R & 127) * 8 + (d0 >> 3)] = res;
}

extern "C" void kernel_launch(void* const* d_in, const int* in_sizes, int n_in,
                              void* d_out, int out_size, void* d_ws, size_t ws_size,
                              hipStream_t stream) {
  const float* x = (const float*)d_in[0];
  const float* Wq = (const float*)d_in[1];
  const float* Wk = (const float*)d_in[2];
  const float* Wv = (const float*)d_in[3];
  const float* Wo = (const float*)d_in[4];
  const int* vl = (const int*)d_in[5];
  float* out = (float*)d_out;

  char* ws = (char*)d_ws;
  const size_t SZ_X = (size_t)Bdim * Sdim * Ddim * sizeof(u16);  // 8 MB
  const size_t SZ_W = (size_t)Ddim * Ddim * sizeof(u16);         // 2 MB
  u16* xt = (u16*)ws; ws += SZ_X;   // staging-tiled x
  u16* WqT = (u16*)ws; ws += SZ_W;  // staging-tiled weights
  u16* WkT = (u16*)ws; ws += SZ_W;
  u16* WvT = (u16*)ws; ws += SZ_W;
  u16* WoT = (u16*)ws; ws += SZ_W;
  u16* Qtb = (u16*)ws; ws += SZ_X;  // attn-tiled Q (Kt layout)
  u16* Ktb = (u16*)ws; ws += SZ_X;  // attn-tiled K
  u16* Vtb = (u16*)ws; ws += SZ_X;  // attn-tiled V^T
  u16* Obt = (u16*)ws; ws += SZ_X;  // staging-tiled attention output

  const size_t PER_SPLIT = (size_t)Bdim * Hdim * Sdim * 64 * sizeof(u16) +
                           (size_t)Bdim * Hdim * Sdim * sizeof(float2);
  size_t used = (size_t)(ws - (char*)d_ws);
  size_t avail = (ws_size > used) ? ws_size - used : 0;
  int NS = (avail >= 4 * PER_SPLIT) ? 4 : (avail >= 2 * PER_SPLIT) ? 2 : 1;
  u16* Opart = (u16*)ws;
  float2* mlp = (float2*)(ws + (size_t)NS * Bdim * Hdim * Sdim * 64 * sizeof(u16));

  cvtx<<<dim3((Bdim * Sdim * Ddim) / (8 * 256)), 256, 0, stream>>>(x, xt);
  transw<<<dim3(32, 32, 4), 256, 0, stream>>>(Wq, Wk, Wv, Wo, WqT, WkT, WvT, WoT);
  // QKV: 128x128 tiles, one dispatch; grid.y = 24 -> (z = y>>3, n-tile = y&7).
  gemm_qkv<<<dim3(32, 24), 256, 0, stream>>>(xt, WqT, WkT, WvT, Qtb, Ktb, Vtb);
  attn_kernel<<<dim3(Sdim / 32, Bdim * Hdim, NS), 64, 0, stream>>>(Qtb, Ktb, Vtb, vl, Obt,
                                                                   Opart, mlp);
  if (NS == 4)
    attn_combine<4><<<dim3(Sdim / 32, Bdim * Hdim), 256, 0, stream>>>(Opart, mlp, Obt);
  else if (NS == 2)
    attn_combine<2><<<dim3(Sdim / 32, Bdim * Hdim), 256, 0, stream>>>(Opart, mlp, Obt);
  // Wo: 64x64 tiles -> 1024 blocks = 4/CU (r24/r25-verified).
  gemm_wo<<<dim3(64, 16), 256, 0, stream>>>(Obt, WoT, out);
}

// Round 28
// 106.516 us; speedup vs baseline: 1.2654x; 1.0235x over previous
//
#include <hip/hip_runtime.h>

#define Bdim 2
#define Sdim 2048
#define Ddim 1024
#define Hdim 16

typedef unsigned short u16;
typedef u16 u16x8 __attribute__((ext_vector_type(8)));
typedef u16 u16x4 __attribute__((ext_vector_type(4)));
typedef unsigned u32x4 __attribute__((ext_vector_type(4)));
typedef __bf16 bf16x8 __attribute__((ext_vector_type(8)));
typedef float f32x4 __attribute__((ext_vector_type(4)));
typedef float f32x16 __attribute__((ext_vector_type(16)));

static __device__ __forceinline__ u16 f2bf(float f) {
  unsigned u = __float_as_uint(f);
  u += 0x7fffu + ((u >> 16) & 1u);
  return (u16)(u >> 16);
}
static __device__ __forceinline__ float bf2f(u16 v) {
  return __uint_as_float((unsigned)v << 16);
}
static __device__ __forceinline__ bf16x8 asbf(u16x8 v) {
  return __builtin_bit_cast(bf16x8, v);
}
static __device__ __forceinline__ f32x4 mfma16(bf16x8 a, bf16x8 b, f32x4 c) {
  return __builtin_amdgcn_mfma_f32_16x16x32_bf16(a, b, c, 0, 0, 0);
}
static __device__ __forceinline__ f32x16 mfma32(bf16x8 a, bf16x8 b, f32x16 c) {
  return __builtin_amdgcn_mfma_f32_32x32x16_bf16(a, b, c, 0, 0, 0);
}

// Staging-order tile cell for [rows][1024] bf16 (gemm operand layout, r16-verified):
// tcell(R,k) = ((R>>7)*16 + (k>>6))*1024 + (R&127)*8 + ((k>>3)&7), cell = 8 u16.
static __device__ __forceinline__ size_t tcell(int R, int k) {
  return ((size_t)(R >> 7) * 16 + (k >> 6)) * 1024 + (R & 127) * 8 + ((k >> 3) & 7);
}

// ------ merged prep: cvtx (blocks 0..2047) + transw (blocks 2048..6143) ------
// Bodies are byte-identical to the r25-verified cvtx/transw kernels; only the
// block-index decomposition changed (saves one launch boundary).
__global__ __launch_bounds__(256) void prep(
    const float* __restrict__ x, u16* __restrict__ xt,
    const float* __restrict__ W0, const float* __restrict__ W1,
    const float* __restrict__ W2, const float* __restrict__ W3,
    u16* __restrict__ T0, u16* __restrict__ T1,
    u16* __restrict__ T2, u16* __restrict__ T3) {
  if (blockIdx.x < 2048) {
    // ---- cvtx body ----
    int i = blockIdx.x * 256 + threadIdx.x;
    const float4* xp = (const float4*)x;
    float4 a = xp[2 * i], b = xp[2 * i + 1];
    u16x8 o;
    o[0] = f2bf(a.x); o[1] = f2bf(a.y); o[2] = f2bf(a.z); o[3] = f2bf(a.w);
    o[4] = f2bf(b.x); o[5] = f2bf(b.y); o[6] = f2bf(b.z); o[7] = f2bf(b.w);
    int R = i >> 7, k = (i & 127) * 8;
    ((u16x8*)xt)[tcell(R, k)] = o;
  } else {
    // ---- transw body; idx encodes (bx=k-tile, by=n-tile, bz=weight) ----
    int idx = blockIdx.x - 2048;
    int bx = idx & 31, by = (idx >> 5) & 31, bz = idx >> 10;
    const float* W = bz == 0 ? W0 : bz == 1 ? W1 : bz == 2 ? W2 : W3;
    u16* T = bz == 0 ? T0 : bz == 1 ? T1 : bz == 2 ? T2 : T3;
    __shared__ float tile[32][33];
    const int t = threadIdx.x;
    const int k0 = bx * 32, n0 = by * 32;
    const int r = t >> 3, cq = (t & 7) * 4;
    float4 v = *(const float4*)(W + (size_t)(k0 + r) * Ddim + n0 + cq);
    tile[r][cq] = v.x; tile[r][cq + 1] = v.y; tile[r][cq + 2] = v.z; tile[r][cq + 3] = v.w;
    __syncthreads();
    u16x4 ov;
    ov[0] = f2bf(tile[cq][r]);
    ov[1] = f2bf(tile[cq + 1][r]);
    ov[2] = f2bf(tile[cq + 2][r]);
    ov[3] = f2bf(tile[cq + 3][r]);
    int n = n0 + r, k = k0 + cq;
    *(u16x4*)(T + tcell(n, k) * 8 + (k & 7)) = ov;
  }
}

// ---------------- QKV GEMM: 128x128 tiles (r25-verified ~35us), attn-tiled outputs ----------------
__global__ __launch_bounds__(256) void gemm_qkv(
    const u16* __restrict__ A,
    const u16* __restrict__ Bt0, const u16* __restrict__ Bt1, const u16* __restrict__ Bt2,
    u16* __restrict__ Qt, u16* __restrict__ Kt, u16* __restrict__ Vt) {
  __shared__ u16 As[128 * 64];
  __shared__ u16 Bs[128 * 64];
  const int zz = blockIdx.y >> 3;
  const u16* Bt = (zz == 0) ? Bt0 : (zz == 1) ? Bt1 : Bt2;

  const int t = threadIdx.x;
  const int lane = t & 63, w = t >> 6;
  const int wm = w >> 1, wn = w & 1;
  const int c = lane & 15, g = lane >> 4;
  const int mb = blockIdx.x, nb = blockIdx.y & 7;
  const float oscale = (zz == 0) ? 0.125f : 1.0f;

  const f32x4 zv = {0.f, 0.f, 0.f, 0.f};
  f32x4 acc[4][4];
#pragma unroll
  for (int m = 0; m < 4; m++)
#pragma unroll
    for (int n = 0; n < 4; n++) acc[m][n] = zv;

  const u16x8* Ac = (const u16x8*)A;
  const u16x8* Bc = (const u16x8*)Bt;
  u16x8 ra[4], rb[4];
#pragma unroll
  for (int i = 0; i < 4; i++) {
    ra[i] = Ac[(size_t)(mb * 16 + 0) * 1024 + t + 256 * i];
    rb[i] = Bc[(size_t)(nb * 16 + 0) * 1024 + t + 256 * i];
  }
#pragma unroll
  for (int i = 0; i < 4; i++) {
    int idx = t + 256 * i;
    int row = idx >> 3, ch = idx & 7;
    int sw = (ch ^ (row & 7)) * 8;
    *(u16x8*)(As + row * 64 + sw) = ra[i];
    *(u16x8*)(Bs + row * 64 + sw) = rb[i];
  }
  __syncthreads();

  for (int kt = 0; kt < 16; ++kt) {
    const bool more = (kt + 1) < 16;
    if (more) {
#pragma unroll
      for (int i = 0; i < 4; i++) {
        ra[i] = Ac[(size_t)(mb * 16 + kt + 1) * 1024 + t + 256 * i];
        rb[i] = Bc[(size_t)(nb * 16 + kt + 1) * 1024 + t + 256 * i];
      }
    }
#pragma unroll
    for (int kh = 0; kh < 2; kh++) {
      bf16x8 af[4], bfr[4];
#pragma unroll
      for (int m = 0; m < 4; m++) {
        int row = wm * 64 + m * 16 + c;
        int chr = kh * 4 + g;
        af[m] = asbf(*(const u16x8*)(As + row * 64 + ((chr ^ (row & 7)) * 8)));
      }
#pragma unroll
      for (int n = 0; n < 4; n++) {
        int row = wn * 64 + n * 16 + c;
        int chr = kh * 4 + g;
        bfr[n] = asbf(*(const u16x8*)(Bs + row * 64 + ((chr ^ (row & 7)) * 8)));
      }
#pragma unroll
      for (int m = 0; m < 4; m++)
#pragma unroll
        for (int n = 0; n < 4; n++) acc[m][n] = mfma16(af[m], bfr[n], acc[m][n]);
    }
    if (more) {
      __syncthreads();
#pragma unroll
      for (int i = 0; i < 4; i++) {
        int idx = t + 256 * i;
        int row = idx >> 3, ch = idx & 7;
        int sw = (ch ^ (row & 7)) * 8;
        *(u16x8*)(As + row * 64 + sw) = ra[i];
        *(u16x8*)(Bs + row * 64 + sw) = rb[i];
      }
      __syncthreads();
    }
  }
  // epilogue: C/D layout col=lane&15, row=4*(lane>>4)+r [m89/m91]
  if (zz < 2) {
    u16* Ct = (zz == 0) ? Qt : Kt;
#pragma unroll
    for (int m = 0; m < 4; m++)
#pragma unroll
      for (int n = 0; n < 4; n++) {
        int col = nb * 128 + wn * 64 + n * 16 + c;
        int Rb = mb * 128 + wm * 64 + m * 16 + 4 * g;
        size_t base = ((size_t)((Rb >> 11) * 16 + (col >> 6)) * 32 + ((Rb >> 6) & 31)) * 4096 +
                      ((col & 63) >> 3) * 512 + (size_t)(Rb & 63) * 8 + (col & 7);
#pragma unroll
        for (int r = 0; r < 4; r++)
          Ct[base + (size_t)r * 8] = f2bf(acc[m][n][r] * oscale);
      }
  } else {
#pragma unroll
    for (int m = 0; m < 4; m++)
#pragma unroll
      for (int n = 0; n < 4; n++) {
        int col = nb * 128 + wn * 64 + n * 16 + c;
        int Rb = mb * 128 + wm * 64 + m * 16 + 4 * g;
        u16x4 ov;
#pragma unroll
        for (int r = 0; r < 4; r++) ov[r] = f2bf(acc[m][n][r]);
        size_t addr = ((size_t)((Rb >> 11) * 16 + (col >> 6)) * 32 + ((Rb >> 6) & 31)) * 4096 +
                      ((Rb & 63) >> 3) * 512 + (size_t)(col & 63) * 8 + (Rb & 7);
        *(u16x4*)(Vt + addr) = ov;
      }
  }
}

// ---------------- 64x64-tile GEMM for Wo (f32 out): 1024 blocks = 4/CU (r25-verified) ----------------
__global__ __launch_bounds__(256) void gemm_wo(
    const u16* __restrict__ A, const u16* __restrict__ Bt, float* __restrict__ C) {
  __shared__ u16 As[64 * 64];
  __shared__ u16 Bs[64 * 64];
  const int t = threadIdx.x;
  const int lane = t & 63, w = t >> 6;
  const int wm = w >> 1, wn = w & 1;
  const int c = lane & 15, g = lane >> 4;
  const int mb = blockIdx.x, nb = blockIdx.y;  // 64 m-tiles, 16 n-tiles of 64

  const f32x4 zv = {0.f, 0.f, 0.f, 0.f};
  f32x4 acc[2][2];
#pragma unroll
  for (int m = 0; m < 2; m++)
#pragma unroll
    for (int n = 0; n < 2; n++) acc[m][n] = zv;

  const u16x8* Ac = (const u16x8*)A;
  const u16x8* Bc = (const u16x8*)Bt;
  const size_t abase = (size_t)(mb >> 1) * 16384 + (size_t)(mb & 1) * 512;
  const size_t bbase = (size_t)(nb >> 1) * 16384 + (size_t)(nb & 1) * 512;
  u16x8 ra[2], rb[2];
#pragma unroll
  for (int i = 0; i < 2; i++) {
    ra[i] = Ac[abase + 0 * 1024 + t + 256 * i];
    rb[i] = Bc[bbase + 0 * 1024 + t + 256 * i];
  }
  {
#pragma unroll
    for (int i = 0; i < 2; i++) {
      int idx = t + 256 * i;
      int row = idx >> 3, ch = idx & 7;
      int sw = (ch ^ (row & 7)) * 8;
      *(u16x8*)(As + row * 64 + sw) = ra[i];
      *(u16x8*)(Bs + row * 64 + sw) = rb[i];
    }
  }
  __syncthreads();

  for (int kt = 0; kt < 16; ++kt) {
    const bool more = (kt + 1) < 16;
    if (more) {
#pragma unroll
      for (int i = 0; i < 2; i++) {
        ra[i] = Ac[abase + (size_t)(kt + 1) * 1024 + t + 256 * i];
        rb[i] = Bc[bbase + (size_t)(kt + 1) * 1024 + t + 256 * i];
      }
    }
#pragma unroll
    for (int kh = 0; kh < 2; kh++) {
      bf16x8 af[2], bfr[2];
#pragma unroll
      for (int m = 0; m < 2; m++) {
        int row = wm * 32 + m * 16 + c;
        int chr = kh * 4 + g;
        af[m] = asbf(*(const u16x8*)(As + row * 64 + ((chr ^ (row & 7)) * 8)));
      }
#pragma unroll
      for (int n = 0; n < 2; n++) {
        int row = wn * 32 + n * 16 + c;
        int chr = kh * 4 + g;
        bfr[n] = asbf(*(const u16x8*)(Bs + row * 64 + ((chr ^ (row & 7)) * 8)));
      }
#pragma unroll
      for (int m = 0; m < 2; m++)
#pragma unroll
        for (int n = 0; n < 2; n++) acc[m][n] = mfma16(af[m], bfr[n], acc[m][n]);
    }
    if (more) {
      __syncthreads();
#pragma unroll
      for (int i = 0; i < 2; i++) {
        int idx = t + 256 * i;
        int row = idx >> 3, ch = idx & 7;
        int sw = (ch ^ (row & 7)) * 8;
        *(u16x8*)(As + row * 64 + sw) = ra[i];
        *(u16x8*)(Bs + row * 64 + sw) = rb[i];
      }
      __syncthreads();
    }
  }
#pragma unroll
  for (int m = 0; m < 2; m++)
#pragma unroll
    for (int n = 0; n < 2; n++)
#pragma unroll
      for (int r = 0; r < 4; r++) {
        int row = mb * 64 + wm * 32 + m * 16 + 4 * g + r;
        int col = nb * 64 + wn * 32 + n * 16 + c;
        C[(size_t)row * 1024 + col] = acc[m][n][r];
      }
}

// ---------------- flash attention: all operands tiled (Qt/Kt/Vt) + KV-split ----------------
__global__ __launch_bounds__(64, 4) void attn_kernel(
    const u16* __restrict__ Qt, const u16* __restrict__ Kt,
    const u16* __restrict__ Vt, const int* __restrict__ vlen,
    u16* __restrict__ O, u16* __restrict__ Opart, float2* __restrict__ mlp) {
  __shared__ u16 ot[32][72];
  const int lane = threadIdx.x;
  const int q = lane & 31, hi = lane >> 5;
  const int bh = blockIdx.y, b = bh >> 4, h = bh & 15;
  const int q0 = blockIdx.x * 32;
  const int nv = vlen[b];
  const int NS = gridDim.z, z = blockIdx.z;

  bf16x8 qf[4];
  {
    const u16* Qtile = Qt + ((size_t)bh * 32 + (q0 >> 6)) * 4096;
    int qrow = (q0 & 63) + q;
#pragma unroll
    for (int s = 0; s < 4; s++)
      qf[s] = asbf(*(const u16x8*)(Qtile + (2 * s + hi) * 512 + qrow * 8));
  }

  f32x16 o0, o1;
#pragma unroll
  for (int r = 0; r < 16; r++) { o0[r] = 0.f; o1[r] = 0.f; }
  float m = -3.0e38f, l = 0.f;

  const int nt = (nv + 63) >> 6;
  const int chunk = (nt + NS - 1) / NS;
  const int t0 = z * chunk;
  const int t1 = min(nt, t0 + chunk);
  for (int kt = t0; kt < t1; ++kt) {
    const int k0 = kt * 64;
    const u16* Ktile = Kt + ((size_t)bh * 32 + kt) * 4096;
    const u16* Vtile = Vt + ((size_t)bh * 32 + kt) * 4096;
    f32x16 sc[2];
#pragma unroll
    for (int kb = 0; kb < 2; kb++) {
      f32x16 acc;
#pragma unroll
      for (int r = 0; r < 16; r++) acc[r] = 0.f;
#pragma unroll
      for (int s = 0; s < 4; s++) {
        bf16x8 kf = asbf(*(const u16x8*)(Ktile + (2 * s + hi) * 512 + (kb * 32 + q) * 8));
        acc = mfma32(kf, qf[s], acc);
      }
      sc[kb] = acc;
    }
    if (k0 + 64 > nv) {
#pragma unroll
      for (int kb = 0; kb < 2; kb++)
#pragma unroll
        for (int r = 0; r < 16; r++) {
          int key = k0 + kb * 32 + (r & 3) + 8 * (r >> 2) + 4 * hi;
          if (key >= nv) sc[kb][r] = -1e30f;
        }
    }
    float mx[16];
#pragma unroll
    for (int r = 0; r < 16; r++) mx[r] = fmaxf(sc[0][r], sc[1][r]);
#pragma unroll
    for (int st = 8; st > 0; st >>= 1)
#pragma unroll
      for (int r = 0; r < st; r++) mx[r] = fmaxf(mx[r], mx[r + st]);
    float tm = fmaxf(mx[0], __shfl_xor(mx[0], 32));
    if (!__all(tm <= m + 8.f)) {
      float mn = fmaxf(m, tm);
      float al = __expf(m - mn);
#pragma unroll
      for (int r = 0; r < 16; r++) { o0[r] *= al; o1[r] *= al; }
      l *= al;
      m = mn;
    }
    unsigned pw[4][4];
    float s0 = 0.f, s1 = 0.f, s2 = 0.f, s3 = 0.f;
#pragma unroll
    for (int kb = 0; kb < 2; kb++)
#pragma unroll
      for (int hh = 0; hh < 2; hh++)
#pragma unroll
        for (int wi = 0; wi < 4; wi++) {
          float e0 = __expf(sc[kb][hh * 8 + wi * 2] - m);
          float e1 = __expf(sc[kb][hh * 8 + wi * 2 + 1] - m);
          if (wi == 0) s0 += e0 + e1;
          else if (wi == 1) s1 += e0 + e1;
          else if (wi == 2) s2 += e0 + e1;
          else s3 += e0 + e1;
          asm("v_cvt_pk_bf16_f32 %0, %1, %2"
              : "=v"(pw[kb * 2 + hh][wi]) : "v"(e0), "v"(e1));
        }
    float ssum = (s0 + s1) + (s2 + s3);
    ssum += __shfl_xor(ssum, 32);
    l += ssum;
#pragma unroll
    for (int f = 0; f < 4; f++) {
      asm("v_permlane32_swap_b32 %0, %1" : "+v"(pw[f][0]), "+v"(pw[f][2]));
      asm("v_permlane32_swap_b32 %0, %1" : "+v"(pw[f][1]), "+v"(pw[f][3]));
    }
#pragma unroll
    for (int f = 0; f < 4; f++) {
      u32x4 wv = {pw[f][0], pw[f][1], pw[f][2], pw[f][3]};
      bf16x8 pa = __builtin_bit_cast(bf16x8, wv);
      bf16x8 va = asbf(*(const u16x8*)(Vtile + (2 * f + hi) * 512 + q * 8));
      bf16x8 vb = asbf(*(const u16x8*)(Vtile + (2 * f + hi) * 512 + (32 + q) * 8));
      o0 = mfma32(va, pa, o0);
      o1 = mfma32(vb, pa, o1);
    }
  }
  const float scale = (NS == 1) ? (1.f / l) : 1.f;
#pragma unroll
  for (int r = 0; r < 16; r++) {
    const int dh = (r & 3) + 8 * (r >> 2) + 4 * hi;
    ot[q][dh] = f2bf(o0[r] * scale);
    ot[q][32 + dh] = f2bf(o1[r] * scale);
  }
  asm volatile("s_waitcnt lgkmcnt(0)" ::: "memory");
  __builtin_amdgcn_sched_barrier(0);
  if (NS == 1) {
    int R = b * Sdim + q0 + q;
    size_t cellbase = ((size_t)(R >> 7) * 16 + h) * 1024 + (R & 127) * 8 + hi * 4;
#pragma unroll
    for (int j = 0; j < 4; j++)
      ((u16x8*)O)[cellbase + j] = *(const u16x8*)(&ot[q][hi * 32 + j * 8]);
  } else {
    u16* op = Opart + ((size_t)(z * 32 + bh) * Sdim + q0 + q) * 64 + hi * 32;
#pragma unroll
    for (int j = 0; j < 4; j++)
      *(u16x8*)(op + j * 8) = *(const u16x8*)(&ot[q][hi * 32 + j * 8]);
    if (hi == 0)
      mlp[(size_t)(z * 32 + bh) * Sdim + q0 + q] = make_float2(m, l);
  }
}

// ---- combine NS split partials -> O in staging-tiled layout (Wo gemm A) ----
template <int NS>
__global__ __launch_bounds__(256) void attn_combine(
    const u16* __restrict__ Opart, const float2* __restrict__ mlp,
    u16* __restrict__ O) {
  const int t = threadIdx.x;
  const int bh = blockIdx.y, b = bh >> 4, h = bh & 15;
  const int q = blockIdx.x * 32 + (t >> 3);
  const int d0 = (t & 7) * 8;
  float2 ml[NS];
  float M = -3.0e38f;
#pragma unroll
  for (int z = 0; z < NS; z++) {
    ml[z] = mlp[(size_t)(z * 32 + bh) * Sdim + q];
    M = fmaxf(M, ml[z].x);
  }
  float acc[8];
#pragma unroll
  for (int i = 0; i < 8; i++) acc[i] = 0.f;
  float wsum = 0.f;
#pragma unroll
  for (int z = 0; z < NS; z++) {
    float w = __expf(ml[z].x - M);
    wsum += w * ml[z].y;
    u16x8 ov = *(const u16x8*)(Opart + ((size_t)(z * 32 + bh) * Sdim + q) * 64 + d0);
#pragma unroll
    for (int i = 0; i < 8; i++) acc[i] += w * bf2f(ov[i]);
  }
  const float inv = 1.f / wsum;
  u16x8 res;
#pragma unroll
  for (int i = 0; i < 8; i++) res[i] = f2bf(acc[i] * inv);
  int R = b * Sdim + q;
  ((u16x8*)O)[((size_t)(R >> 7) * 16 + h) * 1024 + (R & 127) * 8 + (d0 >> 3)] = res;
}

extern "C" void kernel_launch(void* const* d_in, const int* in_sizes, int n_in,
                              void* d_out, int out_size, void* d_ws, size_t ws_size,
                              hipStream_t stream) {
  const float* x = (const float*)d_in[0];
  const float* Wq = (const float*)d_in[1];
  const float* Wk = (const float*)d_in[2];
  const float* Wv = (const float*)d_in[3];
  const float* Wo = (const float*)d_in[4];
  const int* vl = (const int*)d_in[5];
  float* out = (float*)d_out;

  char* ws = (char*)d_ws;
  const size_t SZ_X = (size_t)Bdim * Sdim * Ddim * sizeof(u16);  // 8 MB
  const size_t SZ_W = (size_t)Ddim * Ddim * sizeof(u16);         // 2 MB
  u16* xt = (u16*)ws; ws += SZ_X;   // staging-tiled x
  u16* WqT = (u16*)ws; ws += SZ_W;  // staging-tiled weights
  u16* WkT = (u16*)ws; ws += SZ_W;
  u16* WvT = (u16*)ws; ws += SZ_W;
  u16* WoT = (u16*)ws; ws += SZ_W;
  u16* Qtb = (u16*)ws; ws += SZ_X;  // attn-tiled Q (Kt layout)
  u16* Ktb = (u16*)ws; ws += SZ_X;  // attn-tiled K
  u16* Vtb = (u16*)ws; ws += SZ_X;  // attn-tiled V^T
  u16* Obt = (u16*)ws; ws += SZ_X;  // staging-tiled attention output

  const size_t PER_SPLIT = (size_t)Bdim * Hdim * Sdim * 64 * sizeof(u16) +
                           (size_t)Bdim * Hdim * Sdim * sizeof(float2);
  size_t used = (size_t)(ws - (char*)d_ws);
  size_t avail = (ws_size > used) ? ws_size - used : 0;
  int NS = (avail >= 4 * PER_SPLIT) ? 4 : (avail >= 2 * PER_SPLIT) ? 2 : 1;
  u16* Opart = (u16*)ws;
  float2* mlp = (float2*)(ws + (size_t)NS * Bdim * Hdim * Sdim * 64 * sizeof(u16));

  // merged cvtx+transw: blocks [0,2048) cast x, [2048,6144) transpose weights.
  prep<<<dim3(6144), 256, 0, stream>>>(x, xt, Wq, Wk, Wv, Wo, WqT, WkT, WvT, WoT);
  // QKV: 128x128 tiles, one dispatch; grid.y = 24 -> (z = y>>3, n-tile = y&7).
  gemm_qkv<<<dim3(32, 24), 256, 0, stream>>>(xt, WqT, WkT, WvT, Qtb, Ktb, Vtb);
  attn_kernel<<<dim3(Sdim / 32, Bdim * Hdim, NS), 64, 0, stream>>>(Qtb, Ktb, Vtb, vl, Obt,
                                                                   Opart, mlp);
  if (NS == 4)
    attn_combine<4><<<dim3(Sdim / 32, Bdim * Hdim), 256, 0, stream>>>(Opart, mlp, Obt);
  else if (NS == 2)
    attn_combine<2><<<dim3(Sdim / 32, Bdim * Hdim), 256, 0, stream>>>(Opart, mlp, Obt);
  // Wo: 64x64 tiles -> 1024 blocks = 4/CU (r24/r25-verified).
  gemm_wo<<<dim3(64, 16), 256, 0, stream>>>(Obt, WoT, out);
}